// Round 2
// baseline (710.826 us; speedup 1.0000x reference)
//
#include <hip/hip_runtime.h>
#include <hip/hip_bf16.h>
#include <cstdint>
#include <cstddef>

#define S_LEN 2048
#define HID   4096
#define HD    128
#define NH    32
#define NKV   8
#define KVW   (NKV * HD)        /* 1024 */
#define QKVN  (HID + 2 * KVW)   /* 6144 */

typedef __bf16 bf16x8_t __attribute__((ext_vector_type(8)));
typedef float  f32x4_t  __attribute__((ext_vector_type(4)));
typedef unsigned short u16x8_t __attribute__((ext_vector_type(8)));

__device__ __forceinline__ unsigned short f2b(float f) {
  unsigned u = __float_as_uint(f);
  u += 0x7FFFu + ((u >> 16) & 1u);
  return (unsigned short)(u >> 16);
}
__device__ __forceinline__ float b2f(unsigned short v) {
  return __uint_as_float(((unsigned)v) << 16);
}
__device__ __forceinline__ void gld_lds16(const void* g, void* l) {
  __builtin_amdgcn_global_load_lds(
      (const __attribute__((address_space(1))) void*)g,
      (__attribute__((address_space(3))) void*)l, 16, 0, 0);
}

// ---------------- fp32 -> bf16 conversion ----------------
__global__ void cvt_kernel(const float* __restrict__ src,
                           unsigned short* __restrict__ dst, int n4) {
  int i = blockIdx.x * blockDim.x + threadIdx.x;
  int stride = gridDim.x * blockDim.x;
  for (; i < n4; i += stride) {
    float4 v = reinterpret_cast<const float4*>(src)[i];
    ushort4 o;
    o.x = f2b(v.x); o.y = f2b(v.y); o.z = f2b(v.z); o.w = f2b(v.w);
    reinterpret_cast<ushort4*>(dst)[i] = o;
  }
}

// ---------------- RoPE (in-place on bf16 Q and K) ----------------
__global__ void rope_kernel(unsigned short* __restrict__ Q,
                            unsigned short* __restrict__ Kb,
                            const int* __restrict__ pos_ids) {
  const int total = S_LEN * (NH + NKV) * 64;
  int idx = blockIdx.x * blockDim.x + threadIdx.x;
  int stride = gridDim.x * blockDim.x;
  for (; idx < total; idx += stride) {
    int s   = idx / ((NH + NKV) * 64);
    int rem = idx % ((NH + NKV) * 64);
    int hp  = rem >> 6;
    int i   = rem & 63;
    unsigned short* ptr; int W, h;
    if (hp < NH) { ptr = Q;  W = HID; h = hp; }
    else         { ptr = Kb; W = KVW; h = hp - NH; }
    float pos = (float)pos_ids[s];
    float ang = pos * __expf(-(float)i * 0.14391156516f); // ln(10000)/64
    float sn, cs;
    sincosf(ang, &sn, &cs);
    size_t base = (size_t)s * W + (size_t)h * HD + i;
    float lo = b2f(ptr[base]);
    float hi = b2f(ptr[base + 64]);
    ptr[base]      = f2b(lo * cs - hi * sn);
    ptr[base + 64] = f2b(hi * cs + lo * sn);
  }
}

// ---------------- GEMM: C = A(MxK) * B(NxK)^T, bf16 in, MODE epilogue ----------------
// MODE 0: bf16 out to C0 (ld = N)
// MODE 1: fp32 out to C0 (ld = N)
// MODE 2: QKV split: cols [0,4096) -> C0 (ld 4096), [4096,5120) -> C1 (ld 1024),
//         [5120,6144) -> C2 (ld 1024), all bf16
template <int MODE>
__global__ __launch_bounds__(256) void gemm_bt_kernel(
    const unsigned short* __restrict__ A, const unsigned short* __restrict__ B,
    void* __restrict__ C0, void* __restrict__ C1, void* __restrict__ C2,
    int N, int K) {
  __shared__ unsigned short At[128 * 32];
  __shared__ unsigned short Bt[128 * 32];
  const int tid  = threadIdx.x;
  const int lane = tid & 63;
  const int wave = tid >> 6;
  const int wr = (wave >> 1) * 64;
  const int wc = (wave & 1) * 64;
  const int bm = blockIdx.y * 128;
  const int bn = blockIdx.x * 128;

  f32x4_t acc[4][4];
#pragma unroll
  for (int m = 0; m < 4; ++m)
#pragma unroll
    for (int n = 0; n < 4; ++n)
      acc[m][n] = f32x4_t{0.f, 0.f, 0.f, 0.f};

  const int sr1 = tid >> 2;
  const int sc1 = (tid & 3) * 8;
  const int sr2 = (tid + 256) >> 2;
  const int sc2 = ((tid + 256) & 3) * 8;
  const int lr  = lane & 15;
  const int lk  = (lane >> 4) * 8;

  for (int kt = 0; kt < K; kt += 32) {
    gld_lds16(A + (size_t)(bm + sr1) * K + kt + sc1, &At[sr1 * 32 + sc1]);
    gld_lds16(B + (size_t)(bn + sr1) * K + kt + sc1, &Bt[sr1 * 32 + sc1]);
    gld_lds16(A + (size_t)(bm + sr2) * K + kt + sc2, &At[sr2 * 32 + sc2]);
    gld_lds16(B + (size_t)(bn + sr2) * K + kt + sc2, &Bt[sr2 * 32 + sc2]);
    __syncthreads();
    bf16x8_t af[4], bfr[4];
#pragma unroll
    for (int m = 0; m < 4; ++m)
      af[m] = *(const bf16x8_t*)(const void*)&At[(wr + m * 16 + lr) * 32 + lk];
#pragma unroll
    for (int n = 0; n < 4; ++n)
      bfr[n] = *(const bf16x8_t*)(const void*)&Bt[(wc + n * 16 + lr) * 32 + lk];
#pragma unroll
    for (int m = 0; m < 4; ++m)
#pragma unroll
      for (int n = 0; n < 4; ++n)
        acc[m][n] = __builtin_amdgcn_mfma_f32_16x16x32_bf16(af[m], bfr[n], acc[m][n], 0, 0, 0);
    __syncthreads();
  }

  const int rg = (lane >> 4) * 4;
#pragma unroll
  for (int m = 0; m < 4; ++m) {
#pragma unroll
    for (int n = 0; n < 4; ++n) {
#pragma unroll
      for (int r = 0; r < 4; ++r) {
        const int row = bm + wr + m * 16 + rg + r;
        const int col = bn + wc + n * 16 + lr;
        const float v = acc[m][n][r];
        if constexpr (MODE == 0) {
          ((unsigned short*)C0)[(size_t)row * N + col] = f2b(v);
        } else if constexpr (MODE == 1) {
          ((float*)C0)[(size_t)row * N + col] = v;
        } else {
          if (col < HID)
            ((unsigned short*)C0)[(size_t)row * HID + col] = f2b(v);
          else if (col < HID + KVW)
            ((unsigned short*)C1)[(size_t)row * KVW + (col - HID)] = f2b(v);
          else
            ((unsigned short*)C2)[(size_t)row * KVW + (col - HID - KVW)] = f2b(v);
        }
      }
    }
  }
}

// ---------------- flash attention (causal, GQA 4:1) ----------------
// V^T in LDS: Vt[d * 40 + r]  (d = head dim 0..127, r = kv row 0..31)
// pitch 40 >= 32 for all d (no aliasing), max index 127*40+31 = 5111 < 5120.
// Bank pattern: stride 20 dwords mod 32 -> 8 distinct b128 start banks -> 2-way (free).
__global__ __launch_bounds__(256) void attn_kernel(
    const unsigned short* __restrict__ Q, const unsigned short* __restrict__ K,
    const unsigned short* __restrict__ V, unsigned short* __restrict__ O) {
  __shared__ unsigned short Kl[32][136];
  __shared__ unsigned short Vt[5120];
  __shared__ unsigned short Pl[4][16][40];

  const int tid  = threadIdx.x;
  const int lane = tid & 63;
  const int wave = tid >> 6;
  const int h    = blockIdx.y;
  const int kvh  = h >> 2;
  const int q0   = (gridDim.x - 1 - blockIdx.x) * 64;  // heavy blocks dispatch first
  const int qrow = q0 + wave * 16;
  const int lr   = lane & 15;
  const int lk8  = (lane >> 4) * 8;

  bf16x8_t qf[4];
  {
    const unsigned short* qp = Q + (size_t)(qrow + lr) * HID + (size_t)h * HD;
#pragma unroll
    for (int c = 0; c < 4; ++c)
      qf[c] = *(const bf16x8_t*)(const void*)(qp + c * 32 + lk8);
  }
  f32x4_t oacc[8];
#pragma unroll
  for (int c = 0; c < 8; ++c) oacc[c] = f32x4_t{0.f, 0.f, 0.f, 0.f};
  float m_run[4], l_run[4];
#pragma unroll
  for (int r = 0; r < 4; ++r) { m_run[r] = -1e30f; l_run[r] = 0.f; }

  const int kv_end = q0 + 64;
  const int sr = tid >> 4;
  const int sc = (tid & 15) * 8;

  for (int kv0 = 0; kv0 < kv_end; kv0 += 32) {
    __syncthreads();
#pragma unroll
    for (int i = 0; i < 2; ++i) {
      int r = sr + i * 16;
      const size_t gb = (size_t)(kv0 + r) * KVW + (size_t)kvh * HD + sc;
      u16x8_t kvec = *(const u16x8_t*)(const void*)(K + gb);
      *(u16x8_t*)(void*)&Kl[r][sc] = kvec;
      u16x8_t vvec = *(const u16x8_t*)(const void*)(V + gb);
#pragma unroll
      for (int j = 0; j < 8; ++j) Vt[(sc + j) * 40 + r] = vvec[j];
    }
    __syncthreads();

    f32x4_t sacc[2];
#pragma unroll
    for (int n = 0; n < 2; ++n) {
      sacc[n] = f32x4_t{0.f, 0.f, 0.f, 0.f};
#pragma unroll
      for (int c = 0; c < 4; ++c) {
        bf16x8_t kf = *(const bf16x8_t*)(const void*)&Kl[n * 16 + lr][c * 32 + lk8];
        sacc[n] = __builtin_amdgcn_mfma_f32_16x16x32_bf16(qf[c], kf, sacc[n], 0, 0, 0);
      }
    }

    const float scale = 0.08838834764831845f;  // 1/sqrt(128)
    const int rowb = qrow + (lane >> 4) * 4;
    float p[2][4], mt[4];
#pragma unroll
    for (int r = 0; r < 4; ++r) {
#pragma unroll
      for (int n = 0; n < 2; ++n) {
        float x = sacc[n][r] * scale;
        int col = kv0 + n * 16 + lr;
        if (col > rowb + r) x = -1e30f;
        p[n][r] = x;
      }
      mt[r] = fmaxf(p[0][r], p[1][r]);
    }
#pragma unroll
    for (int off = 1; off < 16; off <<= 1)
#pragma unroll
      for (int r = 0; r < 4; ++r)
        mt[r] = fmaxf(mt[r], __shfl_xor(mt[r], off));

    float rs[4];
#pragma unroll
    for (int r = 0; r < 4; ++r) {
      float m_new = fmaxf(m_run[r], mt[r]);
      float alpha = __expf(m_run[r] - m_new);
      m_run[r] = m_new;
      l_run[r] *= alpha;
#pragma unroll
      for (int c = 0; c < 8; ++c) oacc[c][r] *= alpha;
      float s0 = __expf(p[0][r] - m_new);
      float s1 = __expf(p[1][r] - m_new);
      p[0][r] = s0; p[1][r] = s1;
      rs[r] = s0 + s1;
    }
#pragma unroll
    for (int off = 1; off < 16; off <<= 1)
#pragma unroll
      for (int r = 0; r < 4; ++r)
        rs[r] += __shfl_xor(rs[r], off);
#pragma unroll
    for (int r = 0; r < 4; ++r) l_run[r] += rs[r];

#pragma unroll
    for (int r = 0; r < 4; ++r) {
      int prow = (lane >> 4) * 4 + r;
      Pl[wave][prow][lr]      = f2b(p[0][r]);
      Pl[wave][prow][16 + lr] = f2b(p[1][r]);
    }

    bf16x8_t pf = *(const bf16x8_t*)(const void*)&Pl[wave][lr][lk8];
#pragma unroll
    for (int c = 0; c < 8; ++c) {
      bf16x8_t vf = *(const bf16x8_t*)(const void*)&Vt[(c * 16 + lr) * 40 + lk8];
      oacc[c] = __builtin_amdgcn_mfma_f32_16x16x32_bf16(pf, vf, oacc[c], 0, 0, 0);
    }
  }

#pragma unroll
  for (int r = 0; r < 4; ++r) {
    float inv = 1.f / l_run[r];
    int row = qrow + (lane >> 4) * 4 + r;
#pragma unroll
    for (int c = 0; c < 8; ++c)
      O[(size_t)row * HID + (size_t)h * HD + c * 16 + lr] = f2b(oacc[c][r] * inv);
  }
}

// ---------------- host launch ----------------
extern "C" void kernel_launch(void* const* d_in, const int* in_sizes, int n_in,
                              void* d_out, int out_size, void* d_ws, size_t ws_size,
                              hipStream_t stream) {
  (void)in_sizes; (void)n_in; (void)out_size; (void)ws_size;
  const float* X  = (const float*)d_in[0];
  const float* Wq = (const float*)d_in[1];
  const float* Wk = (const float*)d_in[2];
  const float* Wv = (const float*)d_in[3];
  const float* Wo = (const float*)d_in[4];
  const int*  pos = (const int*)d_in[5];
  float* out = (float*)d_out;

  unsigned short* Xb  = (unsigned short*)d_ws;
  unsigned short* Wqb = Xb  + (size_t)S_LEN * HID;
  unsigned short* Wkb = Wqb + (size_t)HID * HID;    // contiguous with Wqb
  unsigned short* Wvb = Wkb + (size_t)KVW * HID;    // contiguous -> [6144 x 4096] B
  unsigned short* Wob = Wvb + (size_t)KVW * HID;
  unsigned short* Qb  = Wob + (size_t)HID * HID;
  unsigned short* Kb  = Qb  + (size_t)S_LEN * HID;
  unsigned short* Vb  = Kb  + (size_t)S_LEN * KVW;
  unsigned short* AOb = Vb  + (size_t)S_LEN * KVW;

  auto cvt = [&](const float* s, unsigned short* d, size_t n) {
    int n4 = (int)(n / 4);
    int grid = (n4 + 255) / 256;
    if (grid > 4096) grid = 4096;
    cvt_kernel<<<grid, 256, 0, stream>>>(s, d, n4);
  };
  cvt(X,  Xb,  (size_t)S_LEN * HID);
  cvt(Wq, Wqb, (size_t)HID * HID);
  cvt(Wk, Wkb, (size_t)KVW * HID);
  cvt(Wv, Wvb, (size_t)KVW * HID);
  cvt(Wo, Wob, (size_t)HID * HID);

  // QKV projection: one GEMM over concatenated [6144 x 4096] weights
  gemm_bt_kernel<2><<<dim3(QKVN / 128, S_LEN / 128), 256, 0, stream>>>(
      Xb, Wqb, Qb, Kb, Vb, QKVN, HID);

  rope_kernel<<<2048, 256, 0, stream>>>(Qb, Kb, pos);

  attn_kernel<<<dim3(S_LEN / 64, NH), 256, 0, stream>>>(Qb, Kb, Vb, AOb);

  // output projection -> fp32
  gemm_bt_kernel<1><<<dim3(HID / 128, S_LEN / 128), 256, 0, stream>>>(
      AOb, Wob, out, nullptr, nullptr, HID, HID);
}

// Round 3
// 437.413 us; speedup vs baseline: 1.6251x; 1.6251x over previous
//
#include <hip/hip_runtime.h>
#include <hip/hip_bf16.h>
#include <cstdint>
#include <cstddef>

#define S_LEN 2048
#define HID   4096
#define HD    128
#define NH    32
#define NKV   8
#define KVW   (NKV * HD)        /* 1024 */
#define QKVN  (HID + 2 * KVW)   /* 6144 */

typedef __bf16 bf16x8_t __attribute__((ext_vector_type(8)));
typedef float  f32x4_t  __attribute__((ext_vector_type(4)));
typedef unsigned short u16x8_t __attribute__((ext_vector_type(8)));

__device__ __forceinline__ unsigned short f2b(float f) {
  unsigned u = __float_as_uint(f);
  u += 0x7FFFu + ((u >> 16) & 1u);
  return (unsigned short)(u >> 16);
}
__device__ __forceinline__ float b2f(unsigned short v) {
  return __uint_as_float(((unsigned)v) << 16);
}
__device__ __forceinline__ void gld_lds16(const void* g, void* l) {
  __builtin_amdgcn_global_load_lds(
      (const __attribute__((address_space(1))) void*)g,
      (__attribute__((address_space(3))) void*)l, 16, 0, 0);
}

// ---------------- fp32 -> bf16 conversion ----------------
__global__ void cvt_kernel(const float* __restrict__ src,
                           unsigned short* __restrict__ dst, int n4) {
  int i = blockIdx.x * blockDim.x + threadIdx.x;
  int stride = gridDim.x * blockDim.x;
  for (; i < n4; i += stride) {
    float4 v = reinterpret_cast<const float4*>(src)[i];
    ushort4 o;
    o.x = f2b(v.x); o.y = f2b(v.y); o.z = f2b(v.z); o.w = f2b(v.w);
    reinterpret_cast<ushort4*>(dst)[i] = o;
  }
}

// ---------------- RoPE (in-place on bf16 Q and K) ----------------
__global__ void rope_kernel(unsigned short* __restrict__ Q,
                            unsigned short* __restrict__ Kb,
                            const int* __restrict__ pos_ids) {
  const int total = S_LEN * (NH + NKV) * 64;
  int idx = blockIdx.x * blockDim.x + threadIdx.x;
  int stride = gridDim.x * blockDim.x;
  for (; idx < total; idx += stride) {
    int s   = idx / ((NH + NKV) * 64);
    int rem = idx % ((NH + NKV) * 64);
    int hp  = rem >> 6;
    int i   = rem & 63;
    unsigned short* ptr; int W, h;
    if (hp < NH) { ptr = Q;  W = HID; h = hp; }
    else         { ptr = Kb; W = KVW; h = hp - NH; }
    float pos = (float)pos_ids[s];
    float ang = pos * __expf(-(float)i * 0.14391156516f); // ln(10000)/64
    float sn, cs;
    sincosf(ang, &sn, &cs);
    size_t base = (size_t)s * W + (size_t)h * HD + i;
    float lo = b2f(ptr[base]);
    float hi = b2f(ptr[base + 64]);
    ptr[base]      = f2b(lo * cs - hi * sn);
    ptr[base + 64] = f2b(hi * cs + lo * sn);
  }
}

// ---------------- GEMM: C = A(MxK) * B(NxK)^T, bf16 in, MODE epilogue ----------------
// MODE 1: fp32 out to C0 (ld = N)
// MODE 2: QKV split: cols [0,4096) -> C0 bf16 (ld 4096), [4096,5120) -> C1 bf16 (ld 1024),
//         [5120,6144) -> C2 = V TRANSPOSED: C2[(col-5120) * S_LEN + row] (bf16)
template <int MODE>
__global__ __launch_bounds__(256) void gemm_bt_kernel(
    const unsigned short* __restrict__ A, const unsigned short* __restrict__ B,
    void* __restrict__ C0, void* __restrict__ C1, void* __restrict__ C2,
    int N, int K) {
  __shared__ unsigned short At[128 * 32];
  __shared__ unsigned short Bt[128 * 32];
  const int tid  = threadIdx.x;
  const int lane = tid & 63;
  const int wave = tid >> 6;
  const int wr = (wave >> 1) * 64;
  const int wc = (wave & 1) * 64;
  const int bm = blockIdx.y * 128;
  const int bn = blockIdx.x * 128;

  f32x4_t acc[4][4];
#pragma unroll
  for (int m = 0; m < 4; ++m)
#pragma unroll
    for (int n = 0; n < 4; ++n)
      acc[m][n] = f32x4_t{0.f, 0.f, 0.f, 0.f};

  const int sr1 = tid >> 2;
  const int sc1 = (tid & 3) * 8;
  const int sr2 = (tid + 256) >> 2;
  const int sc2 = ((tid + 256) & 3) * 8;
  const int lr  = lane & 15;
  const int lk  = (lane >> 4) * 8;

  for (int kt = 0; kt < K; kt += 32) {
    gld_lds16(A + (size_t)(bm + sr1) * K + kt + sc1, &At[sr1 * 32 + sc1]);
    gld_lds16(B + (size_t)(bn + sr1) * K + kt + sc1, &Bt[sr1 * 32 + sc1]);
    gld_lds16(A + (size_t)(bm + sr2) * K + kt + sc2, &At[sr2 * 32 + sc2]);
    gld_lds16(B + (size_t)(bn + sr2) * K + kt + sc2, &Bt[sr2 * 32 + sc2]);
    __syncthreads();
    bf16x8_t af[4], bfr[4];
#pragma unroll
    for (int m = 0; m < 4; ++m)
      af[m] = *(const bf16x8_t*)(const void*)&At[(wr + m * 16 + lr) * 32 + lk];
#pragma unroll
    for (int n = 0; n < 4; ++n)
      bfr[n] = *(const bf16x8_t*)(const void*)&Bt[(wc + n * 16 + lr) * 32 + lk];
#pragma unroll
    for (int m = 0; m < 4; ++m)
#pragma unroll
      for (int n = 0; n < 4; ++n)
        acc[m][n] = __builtin_amdgcn_mfma_f32_16x16x32_bf16(af[m], bfr[n], acc[m][n], 0, 0, 0);
    __syncthreads();
  }

  const int rg = (lane >> 4) * 4;
#pragma unroll
  for (int m = 0; m < 4; ++m) {
#pragma unroll
    for (int n = 0; n < 4; ++n) {
      const int row0 = bm + wr + m * 16 + rg;
      const int col  = bn + wc + n * 16 + lr;
      if constexpr (MODE == 1) {
#pragma unroll
        for (int r = 0; r < 4; ++r)
          ((float*)C0)[(size_t)(row0 + r) * N + col] = acc[m][n][r];
      } else {
        if (col < HID) {
#pragma unroll
          for (int r = 0; r < 4; ++r)
            ((unsigned short*)C0)[(size_t)(row0 + r) * HID + col] = f2b(acc[m][n][r]);
        } else if (col < HID + KVW) {
#pragma unroll
          for (int r = 0; r < 4; ++r)
            ((unsigned short*)C1)[(size_t)(row0 + r) * KVW + (col - HID)] = f2b(acc[m][n][r]);
        } else {
          // V transposed: Vt[c2][row], 4 consecutive rows -> one 8B store
          const int c2 = col - HID - KVW;
          ushort4 w;
          w.x = f2b(acc[m][n][0]); w.y = f2b(acc[m][n][1]);
          w.z = f2b(acc[m][n][2]); w.w = f2b(acc[m][n][3]);
          *(ushort4*)(void*)&((unsigned short*)C2)[(size_t)c2 * S_LEN + row0] = w;
        }
      }
    }
  }
}

// ---------------- flash attention v2 (causal, GQA 4:1) ----------------
// Swapped QK^T (S^T = mfma(K,Q)): softmax reduce = 2 shfl; wide exp.
// KVBLK=64. V pre-transposed globally (VtG[kv_head*HD + d][s]).
// Block: 64 q rows x 1 head, 4 waves x 16 q rows. Deferred rescale (THR=8).
__global__ __launch_bounds__(256) void attn_kernel(
    const unsigned short* __restrict__ Q, const unsigned short* __restrict__ K,
    const unsigned short* __restrict__ VtG, unsigned short* __restrict__ O) {
  __shared__ unsigned short Kl[64][136];
  __shared__ unsigned short Vt[128][72];
  __shared__ unsigned short Pl[4][16][72];

  const int tid  = threadIdx.x;
  const int lane = tid & 63;
  const int wave = tid >> 6;
  const int h    = blockIdx.y;
  const int kvh  = h >> 2;
  const int q0   = (gridDim.x - 1 - blockIdx.x) * 64;  // heavy blocks first
  const int qrow = q0 + wave * 16;
  const int lr   = lane & 15;
  const int g    = lane >> 4;
  const int lk8  = g * 8;

  // Q fragment (B-operand of swapped QK^T == old A-operand load)
  bf16x8_t qf[4];
  {
    const unsigned short* qp = Q + (size_t)(qrow + lr) * HID + (size_t)h * HD;
#pragma unroll
    for (int c = 0; c < 4; ++c)
      qf[c] = *(const bf16x8_t*)(const void*)(qp + c * 32 + lk8);
  }

  f32x4_t oacc[8];
#pragma unroll
  for (int c = 0; c < 8; ++c) oacc[c] = f32x4_t{0.f, 0.f, 0.f, 0.f};
  float m_run = -3e38f, l_run = 0.f;   // per lane, for q-row = qrow + (lane&15)

  const float scale = 0.08838834764831845f;  // 1/sqrt(128)
  const int kv_end = q0 + 64;
  const unsigned short* Vbase = VtG + (size_t)kvh * HD * S_LEN;

  // staging coords
  const int ksr = tid >> 4, ksc = (tid & 15) * 8;   // K: 16 rows/pass x 128 cols
  const int vsr = tid >> 3, vsc = (tid & 7) * 8;    // Vt: 32 rows/pass x 64 cols

  for (int kv0 = 0; kv0 < kv_end; kv0 += 64) {
    u16x8_t kr[4], vr[4];
#pragma unroll
    for (int i = 0; i < 4; ++i)
      kr[i] = *(const u16x8_t*)(const void*)(K + (size_t)(kv0 + ksr + i * 16) * KVW +
                                             (size_t)kvh * HD + ksc);
#pragma unroll
    for (int i = 0; i < 4; ++i)
      vr[i] = *(const u16x8_t*)(const void*)(Vbase + (size_t)(vsr + i * 32) * S_LEN +
                                             kv0 + vsc);
    __syncthreads();  // prior tile fully consumed
#pragma unroll
    for (int i = 0; i < 4; ++i)
      *(u16x8_t*)(void*)&Kl[ksr + i * 16][ksc] = kr[i];
#pragma unroll
    for (int i = 0; i < 4; ++i)
      *(u16x8_t*)(void*)&Vt[vsr + i * 32][vsc] = vr[i];
    __syncthreads();  // tile ready

    // ---- S^T = K * Q^T : acc col = q (lane&15), row = k ((g*4+r) + 16n) ----
    f32x4_t sacc[4];
#pragma unroll
    for (int n = 0; n < 4; ++n) sacc[n] = f32x4_t{0.f, 0.f, 0.f, 0.f};
#pragma unroll
    for (int c = 0; c < 4; ++c) {
      bf16x8_t qc = qf[c];
#pragma unroll
      for (int n = 0; n < 4; ++n) {
        bf16x8_t kf = *(const bf16x8_t*)(const void*)&Kl[n * 16 + lr][c * 32 + lk8];
        sacc[n] = __builtin_amdgcn_mfma_f32_16x16x32_bf16(kf, qc, sacc[n], 0, 0, 0);
      }
    }

    // ---- softmax over k (register-local 16 values + 2 shfl) ----
    const int qg = qrow + lr;
    const bool diag = (kv0 + 63 > qrow);
    float p[16];
    float mloc = -3e38f;
#pragma unroll
    for (int n = 0; n < 4; ++n)
#pragma unroll
      for (int r = 0; r < 4; ++r) {
        float x = sacc[n][r] * scale;
        if (diag) {
          int kg = kv0 + n * 16 + g * 4 + r;
          if (kg > qg) x = -3e38f;
        }
        p[n * 4 + r] = x;
        mloc = fmaxf(mloc, x);
      }
    mloc = fmaxf(mloc, __shfl_xor(mloc, 16));
    mloc = fmaxf(mloc, __shfl_xor(mloc, 32));

    if (__any(mloc > m_run + 8.f)) {          // T13 deferred rescale
      float m_new = fmaxf(m_run, mloc);
      float alpha = __expf(m_run - m_new);
      float a4[4];
#pragma unroll
      for (int r = 0; r < 4; ++r) a4[r] = __shfl(alpha, g * 4 + r);
#pragma unroll
      for (int c = 0; c < 8; ++c)
#pragma unroll
        for (int r = 0; r < 4; ++r) oacc[c][r] *= a4[r];
      l_run *= alpha;
      m_run = m_new;
    }

    float ssum = 0.f;
#pragma unroll
    for (int i = 0; i < 16; ++i) {
      float e = __expf(p[i] - m_run);
      p[i] = e;
      ssum += e;
    }
    ssum += __shfl_xor(ssum, 16);
    ssum += __shfl_xor(ssum, 32);
    l_run += ssum;

    // ---- store P (transposing S^T -> row-major P[q][k]) ----
#pragma unroll
    for (int n = 0; n < 4; ++n) {
      ushort4 w;
      w.x = f2b(p[n * 4 + 0]); w.y = f2b(p[n * 4 + 1]);
      w.z = f2b(p[n * 4 + 2]); w.w = f2b(p[n * 4 + 3]);
      *(ushort4*)(void*)&Pl[wave][lr][n * 16 + g * 4] = w;
    }
    // per-wave LDS write->read: compiler inserts lgkmcnt, no barrier needed

    // ---- PV: out += P * V ----
#pragma unroll
    for (int half = 0; half < 2; ++half) {
      bf16x8_t pf = *(const bf16x8_t*)(const void*)&Pl[wave][lr][half * 32 + lk8];
#pragma unroll
      for (int c = 0; c < 8; ++c) {
        bf16x8_t vf = *(const bf16x8_t*)(const void*)&Vt[c * 16 + lr][half * 32 + lk8];
        oacc[c] = __builtin_amdgcn_mfma_f32_16x16x32_bf16(pf, vf, oacc[c], 0, 0, 0);
      }
    }
  }

  // ---- epilogue: divide by l (fetch l for q = g*4+r) and store ----
  float linv[4];
#pragma unroll
  for (int r = 0; r < 4; ++r) linv[r] = 1.f / __shfl(l_run, g * 4 + r);
#pragma unroll
  for (int r = 0; r < 4; ++r) {
    int row = qrow + g * 4 + r;
#pragma unroll
    for (int c = 0; c < 8; ++c)
      O[(size_t)row * HID + (size_t)h * HD + c * 16 + lr] = f2b(oacc[c][r] * linv[r]);
  }
}

// ---------------- host launch ----------------
extern "C" void kernel_launch(void* const* d_in, const int* in_sizes, int n_in,
                              void* d_out, int out_size, void* d_ws, size_t ws_size,
                              hipStream_t stream) {
  (void)in_sizes; (void)n_in; (void)out_size; (void)ws_size;
  const float* X  = (const float*)d_in[0];
  const float* Wq = (const float*)d_in[1];
  const float* Wk = (const float*)d_in[2];
  const float* Wv = (const float*)d_in[3];
  const float* Wo = (const float*)d_in[4];
  const int*  pos = (const int*)d_in[5];
  float* out = (float*)d_out;

  unsigned short* Xb  = (unsigned short*)d_ws;
  unsigned short* Wqb = Xb  + (size_t)S_LEN * HID;
  unsigned short* Wkb = Wqb + (size_t)HID * HID;    // contiguous with Wqb
  unsigned short* Wvb = Wkb + (size_t)KVW * HID;    // contiguous -> [6144 x 4096] B
  unsigned short* Wob = Wvb + (size_t)KVW * HID;
  unsigned short* Qb  = Wob + (size_t)HID * HID;
  unsigned short* Kb  = Qb  + (size_t)S_LEN * HID;
  unsigned short* VtB = Kb  + (size_t)S_LEN * KVW;  // V^T: [KVW][S_LEN]
  unsigned short* AOb = VtB + (size_t)S_LEN * KVW;

  auto cvt = [&](const float* s, unsigned short* d, size_t n) {
    int n4 = (int)(n / 4);
    int grid = (n4 + 255) / 256;
    if (grid > 4096) grid = 4096;
    cvt_kernel<<<grid, 256, 0, stream>>>(s, d, n4);
  };
  cvt(X,  Xb,  (size_t)S_LEN * HID);
  cvt(Wq, Wqb, (size_t)HID * HID);
  cvt(Wk, Wkb, (size_t)KVW * HID);
  cvt(Wv, Wvb, (size_t)KVW * HID);
  cvt(Wo, Wob, (size_t)HID * HID);

  // QKV projection: one GEMM over concatenated [6144 x 4096] weights; V written transposed
  gemm_bt_kernel<2><<<dim3(QKVN / 128, S_LEN / 128), 256, 0, stream>>>(
      Xb, Wqb, Qb, Kb, VtB, QKVN, HID);

  rope_kernel<<<2048, 256, 0, stream>>>(Qb, Kb, pos);

  attn_kernel<<<dim3(S_LEN / 64, NH), 256, 0, stream>>>(Qb, Kb, VtB, AOb);

  // output projection -> fp32
  gemm_bt_kernel<1><<<dim3(HID / 128, S_LEN / 128), 256, 0, stream>>>(
      AOb, Wob, out, nullptr, nullptr, HID, HID);
}

// Round 4
// 411.780 us; speedup vs baseline: 1.7262x; 1.0622x over previous
//
#include <hip/hip_runtime.h>
#include <hip/hip_bf16.h>
#include <cstdint>
#include <cstddef>

#define S_LEN 2048
#define HID   4096
#define HD    128
#define NH    32
#define NKV   8
#define KVW   (NKV * HD)        /* 1024 */
#define QKVN  (HID + 2 * KVW)   /* 6144 */

typedef __bf16 bf16x8_t __attribute__((ext_vector_type(8)));
typedef float  f32x4_t  __attribute__((ext_vector_type(4)));
typedef unsigned short u16x8_t __attribute__((ext_vector_type(8)));

__device__ __forceinline__ unsigned short f2b(float f) {
  unsigned u = __float_as_uint(f);
  u += 0x7FFFu + ((u >> 16) & 1u);
  return (unsigned short)(u >> 16);
}
__device__ __forceinline__ float b2f(unsigned short v) {
  return __uint_as_float(((unsigned)v) << 16);
}
__device__ __forceinline__ void gld_lds16(const void* g, void* l) {
  __builtin_amdgcn_global_load_lds(
      (const __attribute__((address_space(1))) void*)g,
      (__attribute__((address_space(3))) void*)l, 16, 0, 0);
}

// ---------------- fp32 -> bf16 conversion ----------------
__global__ void cvt_kernel(const float* __restrict__ src,
                           unsigned short* __restrict__ dst, int n4) {
  int i = blockIdx.x * blockDim.x + threadIdx.x;
  int stride = gridDim.x * blockDim.x;
  for (; i < n4; i += stride) {
    float4 v = reinterpret_cast<const float4*>(src)[i];
    ushort4 o;
    o.x = f2b(v.x); o.y = f2b(v.y); o.z = f2b(v.z); o.w = f2b(v.w);
    reinterpret_cast<ushort4*>(dst)[i] = o;
  }
}

// ---------------- RoPE (in-place on bf16 Q and K) ----------------
__global__ void rope_kernel(unsigned short* __restrict__ Q,
                            unsigned short* __restrict__ Kb,
                            const int* __restrict__ pos_ids) {
  const int total = S_LEN * (NH + NKV) * 64;
  int idx = blockIdx.x * blockDim.x + threadIdx.x;
  int stride = gridDim.x * blockDim.x;
  for (; idx < total; idx += stride) {
    int s   = idx / ((NH + NKV) * 64);
    int rem = idx % ((NH + NKV) * 64);
    int hp  = rem >> 6;
    int i   = rem & 63;
    unsigned short* ptr; int W, h;
    if (hp < NH) { ptr = Q;  W = HID; h = hp; }
    else         { ptr = Kb; W = KVW; h = hp - NH; }
    float pos = (float)pos_ids[s];
    float ang = pos * __expf(-(float)i * 0.14391156516f); // ln(10000)/64
    float sn, cs;
    sincosf(ang, &sn, &cs);
    size_t base = (size_t)s * W + (size_t)h * HD + i;
    float lo = b2f(ptr[base]);
    float hi = b2f(ptr[base + 64]);
    ptr[base]      = f2b(lo * cs - hi * sn);
    ptr[base + 64] = f2b(hi * cs + lo * sn);
  }
}

// ---------------- pipelined GEMM: C = A(MxK) * B(NxK)^T ----------------
// BK=32, 4-deep LDS ring, counted vmcnt (never 0 in main loop), raw barriers,
// 2 phases per K-tile with setprio around the MFMA cluster.
// 512 threads = 8 waves (2M x 4N). Per-wave output: (BM/2) x 64.
// MODE 1: fp32 out to C0 (ld = N)
// MODE 2: QKV split: cols [0,4096) -> C0 bf16 (ld 4096), [4096,5120) -> C1 bf16
//         (ld 1024), [5120,6144) -> C2 = V transposed: C2[(col-5120)*S_LEN+row]
template <int BM, int MODE>
__global__ __launch_bounds__(512, 2) void gemm8_kernel(
    const unsigned short* __restrict__ A, const unsigned short* __restrict__ B,
    void* __restrict__ C0, void* __restrict__ C1, void* __restrict__ C2,
    int N, int K) {
  constexpr int BN = 256;
  constexpr int MF = BM / 32;                  // m-frags per wave (8 or 4)
  constexpr int MFH = MF / 2;                  // m-frags per phase
  constexpr int A_BYTES = BM * 32 * 2;         // 16384 or 8192
  constexpr int TILE_BYTES = A_BYTES + BN * 32 * 2;  // 32768 or 24576
  constexpr int NLOADS = TILE_BYTES / 8192;    // 4 or 3 (8KB per wave-wide load)
  __shared__ unsigned short lds[4 * (TILE_BYTES / 2)];

  const int tid  = threadIdx.x;
  const int lane = tid & 63;
  const int wid  = tid >> 6;
  const int wm = wid >> 2, wn = wid & 3;
  const int lr = lane & 15, g = lane >> 4;
  const int bm = blockIdx.y * BM;
  const int bn = blockIdx.x * BN;
  const int nt = K >> 5;

  // stage load j of tile t: linear byte L in [0, TILE_BYTES), A-region then B.
  auto stage_j = [&](int t, int j) {
    const int L = j * 8192 + wid * 1024 + lane * 16;
    const char* src;
    if (L < A_BYTES) {
      src = (const char*)A + ((size_t)(bm + (L >> 6)) * K + t * 32) * 2 + (L & 63);
    } else {
      const int LB = L - A_BYTES;
      src = (const char*)B + ((size_t)(bn + (LB >> 6)) * K + t * 32) * 2 + (LB & 63);
    }
    char* dst = (char*)lds + (t & 3) * TILE_BYTES + L;
    gld_lds16(src, dst);
  };

  // prologue: stage tiles 0,1,2; wait tile 0 landed (tiles 1,2 in flight)
#pragma unroll
  for (int t = 0; t < 3; ++t)
#pragma unroll
    for (int j = 0; j < NLOADS; ++j) stage_j(t, j);
  asm volatile("s_waitcnt vmcnt(%0)" :: "n"(2 * NLOADS) : "memory");
  __builtin_amdgcn_sched_barrier(0);
  __builtin_amdgcn_s_barrier();

  f32x4_t acc[MF][4];
#pragma unroll
  for (int m = 0; m < MF; ++m)
#pragma unroll
    for (int n = 0; n < 4; ++n) acc[m][n] = f32x4_t{0.f, 0.f, 0.f, 0.f};

  bf16x8_t bfr[4];

  for (int t = 0; t < nt; ++t) {
    const char* base = (const char*)lds + (t & 3) * TILE_BYTES;
    const bool st = (t + 3 < nt);

    // ---- phase 0: m-frags [0, MFH), all B-frags ----
    bf16x8_t af[MFH];
#pragma unroll
    for (int m = 0; m < MFH; ++m)
      af[m] = *(const bf16x8_t*)(base + (wm * (BM / 2) + m * 16 + lr) * 64 + g * 16);
#pragma unroll
    for (int n = 0; n < 4; ++n)
      bfr[n] = *(const bf16x8_t*)(base + A_BYTES + (wn * 64 + n * 16 + lr) * 64 + g * 16);
    if (st) { stage_j(t + 3, 0); stage_j(t + 3, 1); }
    __builtin_amdgcn_sched_barrier(0);
    __builtin_amdgcn_s_barrier();
    __builtin_amdgcn_s_setprio(1);
#pragma unroll
    for (int m = 0; m < MFH; ++m)
#pragma unroll
      for (int n = 0; n < 4; ++n)
        acc[m][n] = __builtin_amdgcn_mfma_f32_16x16x32_bf16(af[m], bfr[n], acc[m][n], 0, 0, 0);
    __builtin_amdgcn_s_setprio(0);
    __builtin_amdgcn_sched_barrier(0);
    __builtin_amdgcn_s_barrier();

    // ---- phase 1: m-frags [MFH, MF) ----
#pragma unroll
    for (int m = 0; m < MFH; ++m)
      af[m] = *(const bf16x8_t*)(base + (wm * (BM / 2) + (MFH + m) * 16 + lr) * 64 + g * 16);
    if (st) {
#pragma unroll
      for (int j = 2; j < NLOADS; ++j) stage_j(t + 3, j);
    }
    __builtin_amdgcn_sched_barrier(0);
    __builtin_amdgcn_s_barrier();
    __builtin_amdgcn_s_setprio(1);
#pragma unroll
    for (int m = 0; m < MFH; ++m)
#pragma unroll
      for (int n = 0; n < 4; ++n)
        acc[MFH + m][n] = __builtin_amdgcn_mfma_f32_16x16x32_bf16(af[m], bfr[n], acc[MFH + m][n], 0, 0, 0);
    __builtin_amdgcn_s_setprio(0);

    // ---- tile boundary: counted wait so tile t+1 is resident; never drain ----
    if (t < nt - 3) {
      asm volatile("s_waitcnt vmcnt(%0)" :: "n"(2 * NLOADS) : "memory");
    } else if (t == nt - 3) {
      asm volatile("s_waitcnt vmcnt(%0)" :: "n"(NLOADS) : "memory");
    } else if (t == nt - 2) {
      asm volatile("s_waitcnt vmcnt(0)" ::: "memory");
    }
    __builtin_amdgcn_sched_barrier(0);
    __builtin_amdgcn_s_barrier();
  }

  // ---- epilogue ----
#pragma unroll
  for (int mf = 0; mf < MF; ++mf) {
    const int row0 = bm + wm * (BM / 2) + mf * 16 + g * 4;
#pragma unroll
    for (int nf = 0; nf < 4; ++nf) {
      const int col = bn + wn * 64 + nf * 16 + lr;
      if constexpr (MODE == 1) {
#pragma unroll
        for (int r = 0; r < 4; ++r)
          ((float*)C0)[(size_t)(row0 + r) * N + col] = acc[mf][nf][r];
      } else {
        if (col < HID) {
#pragma unroll
          for (int r = 0; r < 4; ++r)
            ((unsigned short*)C0)[(size_t)(row0 + r) * HID + col] = f2b(acc[mf][nf][r]);
        } else if (col < HID + KVW) {
#pragma unroll
          for (int r = 0; r < 4; ++r)
            ((unsigned short*)C1)[(size_t)(row0 + r) * KVW + (col - HID)] = f2b(acc[mf][nf][r]);
        } else {
          const int c2 = col - HID - KVW;
          ushort4 w;
          w.x = f2b(acc[mf][nf][0]); w.y = f2b(acc[mf][nf][1]);
          w.z = f2b(acc[mf][nf][2]); w.w = f2b(acc[mf][nf][3]);
          *(ushort4*)(void*)&((unsigned short*)C2)[(size_t)c2 * S_LEN + row0] = w;
        }
      }
    }
  }
}

// ---------------- flash attention v2 (causal, GQA 4:1) ----------------
// Swapped QK^T (S^T = mfma(K,Q)): softmax reduce = 2 shfl; wide exp.
// KVBLK=64. V pre-transposed globally (VtG[kv_head*HD + d][s]).
// Block: 64 q rows x 1 head, 4 waves x 16 q rows. Deferred rescale (THR=8).
__global__ __launch_bounds__(256) void attn_kernel(
    const unsigned short* __restrict__ Q, const unsigned short* __restrict__ K,
    const unsigned short* __restrict__ VtG, unsigned short* __restrict__ O) {
  __shared__ unsigned short Kl[64][136];
  __shared__ unsigned short Vt[128][72];
  __shared__ unsigned short Pl[4][16][72];

  const int tid  = threadIdx.x;
  const int lane = tid & 63;
  const int wave = tid >> 6;
  const int h    = blockIdx.y;
  const int kvh  = h >> 2;
  const int q0   = (gridDim.x - 1 - blockIdx.x) * 64;  // heavy blocks first
  const int qrow = q0 + wave * 16;
  const int lr   = lane & 15;
  const int g    = lane >> 4;
  const int lk8  = g * 8;

  bf16x8_t qf[4];
  {
    const unsigned short* qp = Q + (size_t)(qrow + lr) * HID + (size_t)h * HD;
#pragma unroll
    for (int c = 0; c < 4; ++c)
      qf[c] = *(const bf16x8_t*)(const void*)(qp + c * 32 + lk8);
  }

  f32x4_t oacc[8];
#pragma unroll
  for (int c = 0; c < 8; ++c) oacc[c] = f32x4_t{0.f, 0.f, 0.f, 0.f};
  float m_run = -3e38f, l_run = 0.f;

  const float scale = 0.08838834764831845f;  // 1/sqrt(128)
  const int kv_end = q0 + 64;
  const unsigned short* Vbase = VtG + (size_t)kvh * HD * S_LEN;

  const int ksr = tid >> 4, ksc = (tid & 15) * 8;
  const int vsr = tid >> 3, vsc = (tid & 7) * 8;

  for (int kv0 = 0; kv0 < kv_end; kv0 += 64) {
    u16x8_t kr[4], vr[4];
#pragma unroll
    for (int i = 0; i < 4; ++i)
      kr[i] = *(const u16x8_t*)(const void*)(K + (size_t)(kv0 + ksr + i * 16) * KVW +
                                             (size_t)kvh * HD + ksc);
#pragma unroll
    for (int i = 0; i < 4; ++i)
      vr[i] = *(const u16x8_t*)(const void*)(Vbase + (size_t)(vsr + i * 32) * S_LEN +
                                             kv0 + vsc);
    __syncthreads();
#pragma unroll
    for (int i = 0; i < 4; ++i)
      *(u16x8_t*)(void*)&Kl[ksr + i * 16][ksc] = kr[i];
#pragma unroll
    for (int i = 0; i < 4; ++i)
      *(u16x8_t*)(void*)&Vt[vsr + i * 32][vsc] = vr[i];
    __syncthreads();

    f32x4_t sacc[4];
#pragma unroll
    for (int n = 0; n < 4; ++n) sacc[n] = f32x4_t{0.f, 0.f, 0.f, 0.f};
#pragma unroll
    for (int c = 0; c < 4; ++c) {
      bf16x8_t qc = qf[c];
#pragma unroll
      for (int n = 0; n < 4; ++n) {
        bf16x8_t kf = *(const bf16x8_t*)(const void*)&Kl[n * 16 + lr][c * 32 + lk8];
        sacc[n] = __builtin_amdgcn_mfma_f32_16x16x32_bf16(kf, qc, sacc[n], 0, 0, 0);
      }
    }

    const int qg = qrow + lr;
    const bool diag = (kv0 + 63 > qrow);
    float p[16];
    float mloc = -3e38f;
#pragma unroll
    for (int n = 0; n < 4; ++n)
#pragma unroll
      for (int r = 0; r < 4; ++r) {
        float x = sacc[n][r] * scale;
        if (diag) {
          int kg = kv0 + n * 16 + g * 4 + r;
          if (kg > qg) x = -3e38f;
        }
        p[n * 4 + r] = x;
        mloc = fmaxf(mloc, x);
      }
    mloc = fmaxf(mloc, __shfl_xor(mloc, 16));
    mloc = fmaxf(mloc, __shfl_xor(mloc, 32));

    if (__any(mloc > m_run + 8.f)) {
      float m_new = fmaxf(m_run, mloc);
      float alpha = __expf(m_run - m_new);
      float a4[4];
#pragma unroll
      for (int r = 0; r < 4; ++r) a4[r] = __shfl(alpha, g * 4 + r);
#pragma unroll
      for (int c = 0; c < 8; ++c)
#pragma unroll
        for (int r = 0; r < 4; ++r) oacc[c][r] *= a4[r];
      l_run *= alpha;
      m_run = m_new;
    }

    float ssum = 0.f;
#pragma unroll
    for (int i = 0; i < 16; ++i) {
      float e = __expf(p[i] - m_run);
      p[i] = e;
      ssum += e;
    }
    ssum += __shfl_xor(ssum, 16);
    ssum += __shfl_xor(ssum, 32);
    l_run += ssum;

#pragma unroll
    for (int n = 0; n < 4; ++n) {
      ushort4 w;
      w.x = f2b(p[n * 4 + 0]); w.y = f2b(p[n * 4 + 1]);
      w.z = f2b(p[n * 4 + 2]); w.w = f2b(p[n * 4 + 3]);
      *(ushort4*)(void*)&Pl[wave][lr][n * 16 + g * 4] = w;
    }

#pragma unroll
    for (int half = 0; half < 2; ++half) {
      bf16x8_t pf = *(const bf16x8_t*)(const void*)&Pl[wave][lr][half * 32 + lk8];
#pragma unroll
      for (int c = 0; c < 8; ++c) {
        bf16x8_t vf = *(const bf16x8_t*)(const void*)&Vt[c * 16 + lr][half * 32 + lk8];
        oacc[c] = __builtin_amdgcn_mfma_f32_16x16x32_bf16(pf, vf, oacc[c], 0, 0, 0);
      }
    }
  }

  float linv[4];
#pragma unroll
  for (int r = 0; r < 4; ++r) linv[r] = 1.f / __shfl(l_run, g * 4 + r);
#pragma unroll
  for (int r = 0; r < 4; ++r) {
    int row = qrow + g * 4 + r;
#pragma unroll
    for (int c = 0; c < 8; ++c)
      O[(size_t)row * HID + (size_t)h * HD + c * 16 + lr] = f2b(oacc[c][r] * linv[r]);
  }
}

// ---------------- host launch ----------------
extern "C" void kernel_launch(void* const* d_in, const int* in_sizes, int n_in,
                              void* d_out, int out_size, void* d_ws, size_t ws_size,
                              hipStream_t stream) {
  (void)in_sizes; (void)n_in; (void)out_size; (void)ws_size;
  const float* X  = (const float*)d_in[0];
  const float* Wq = (const float*)d_in[1];
  const float* Wk = (const float*)d_in[2];
  const float* Wv = (const float*)d_in[3];
  const float* Wo = (const float*)d_in[4];
  const int*  pos = (const int*)d_in[5];
  float* out = (float*)d_out;

  unsigned short* Xb  = (unsigned short*)d_ws;
  unsigned short* Wqb = Xb  + (size_t)S_LEN * HID;
  unsigned short* Wkb = Wqb + (size_t)HID * HID;    // contiguous with Wqb
  unsigned short* Wvb = Wkb + (size_t)KVW * HID;    // contiguous -> [6144 x 4096] B
  unsigned short* Wob = Wvb + (size_t)KVW * HID;
  unsigned short* Qb  = Wob + (size_t)HID * HID;
  unsigned short* Kb  = Qb  + (size_t)S_LEN * HID;
  unsigned short* VtB = Kb  + (size_t)S_LEN * KVW;  // V^T: [KVW][S_LEN]
  unsigned short* AOb = VtB + (size_t)S_LEN * KVW;

  auto cvt = [&](const float* s, unsigned short* d, size_t n) {
    int n4 = (int)(n / 4);
    int grid = (n4 + 255) / 256;
    if (grid > 4096) grid = 4096;
    cvt_kernel<<<grid, 256, 0, stream>>>(s, d, n4);
  };
  cvt(X,  Xb,  (size_t)S_LEN * HID);
  cvt(Wq, Wqb, (size_t)HID * HID);
  cvt(Wk, Wkb, (size_t)KVW * HID);
  cvt(Wv, Wvb, (size_t)KVW * HID);
  cvt(Wo, Wob, (size_t)HID * HID);

  // QKV projection: 256x256 tiles, grid 24x8 = 192 blocks
  gemm8_kernel<256, 2><<<dim3(QKVN / 256, S_LEN / 256), 512, 0, stream>>>(
      Xb, Wqb, Qb, Kb, VtB, QKVN, HID);

  rope_kernel<<<2048, 256, 0, stream>>>(Qb, Kb, pos);

  attn_kernel<<<dim3(S_LEN / 64, NH), 256, 0, stream>>>(Qb, Kb, VtB, AOb);

  // output projection: 128x256 tiles, grid 16x16 = 256 blocks -> fp32
  gemm8_kernel<128, 1><<<dim3(HID / 256, S_LEN / 128), 512, 0, stream>>>(
      AOb, Wob, out, nullptr, nullptr, HID, HID);
}

// Round 5
// 395.114 us; speedup vs baseline: 1.7990x; 1.0422x over previous
//
#include <hip/hip_runtime.h>
#include <hip/hip_bf16.h>
#include <cstdint>
#include <cstddef>

#define S_LEN 2048
#define HID   4096
#define HD    128
#define NH    32
#define NKV   8
#define KVW   (NKV * HD)        /* 1024 */
#define QKVN  (HID + 2 * KVW)   /* 6144 */

typedef __bf16 bf16x8_t __attribute__((ext_vector_type(8)));
typedef float  f32x4_t  __attribute__((ext_vector_type(4)));
typedef unsigned short u16x8_t __attribute__((ext_vector_type(8)));

__device__ __forceinline__ unsigned short f2b(float f) {
  unsigned u = __float_as_uint(f);
  u += 0x7FFFu + ((u >> 16) & 1u);
  return (unsigned short)(u >> 16);
}
__device__ __forceinline__ float b2f(unsigned short v) {
  return __uint_as_float(((unsigned)v) << 16);
}
__device__ __forceinline__ void gld_lds16(const void* g, void* l) {
  __builtin_amdgcn_global_load_lds(
      (const __attribute__((address_space(1))) void*)g,
      (__attribute__((address_space(3))) void*)l, 16, 0, 0);
}

// ---------------- fp32 -> bf16 conversion ----------------
__global__ void cvt_kernel(const float* __restrict__ src,
                           unsigned short* __restrict__ dst, int n4) {
  int i = blockIdx.x * blockDim.x + threadIdx.x;
  int stride = gridDim.x * blockDim.x;
  for (; i < n4; i += stride) {
    float4 v = reinterpret_cast<const float4*>(src)[i];
    ushort4 o;
    o.x = f2b(v.x); o.y = f2b(v.y); o.z = f2b(v.z); o.w = f2b(v.w);
    reinterpret_cast<ushort4*>(dst)[i] = o;
  }
}

// ---------------- RoPE (in-place on bf16 Q and K) ----------------
__global__ void rope_kernel(unsigned short* __restrict__ Q,
                            unsigned short* __restrict__ Kb,
                            const int* __restrict__ pos_ids) {
  const int total = S_LEN * (NH + NKV) * 64;
  int idx = blockIdx.x * blockDim.x + threadIdx.x;
  int stride = gridDim.x * blockDim.x;
  for (; idx < total; idx += stride) {
    int s   = idx / ((NH + NKV) * 64);
    int rem = idx % ((NH + NKV) * 64);
    int hp  = rem >> 6;
    int i   = rem & 63;
    unsigned short* ptr; int W, h;
    if (hp < NH) { ptr = Q;  W = HID; h = hp; }
    else         { ptr = Kb; W = KVW; h = hp - NH; }
    float pos = (float)pos_ids[s];
    float ang = pos * __expf(-(float)i * 0.14391156516f); // ln(10000)/64
    float sn, cs;
    sincosf(ang, &sn, &cs);
    size_t base = (size_t)s * W + (size_t)h * HD + i;
    float lo = b2f(ptr[base]);
    float hi = b2f(ptr[base + 64]);
    ptr[base]      = f2b(lo * cs - hi * sn);
    ptr[base + 64] = f2b(hi * cs + lo * sn);
  }
}

// ---------------- pipelined GEMM: C = A(MxK) * B(NxK)^T ----------------
// BK=32, 4-deep LDS ring, counted vmcnt (never 0 in main loop), raw barriers,
// 2 phases per K-tile, setprio around MFMA cluster.
// T2 swizzle: LDS byte-col ^= (row&6)<<3 (permutes 16B chunks within 64B rows);
// applied as inverse-permuted GLOBAL source in stage (global_load_lds dst must
// stay linear) + same XOR on ds_read addresses (rule #21: both sides, same
// involution). Read-side XOR folds to a per-thread constant (row&6 == lr&6).
// 512 threads = 8 waves (2M x 4N). Per-wave output: (BM/2) x 64.
// MODE 1: fp32 out to C0 (ld = N)
// MODE 2: QKV split: cols [0,4096) -> C0 bf16 (ld 4096), [4096,5120) -> C1 bf16
//         (ld 1024), [5120,6144) -> C2 = V transposed: C2[(col-5120)*S_LEN+row]
template <int BM, int MODE>
__global__ __launch_bounds__(512, 2) void gemm8_kernel(
    const unsigned short* __restrict__ A, const unsigned short* __restrict__ B,
    void* __restrict__ C0, void* __restrict__ C1, void* __restrict__ C2,
    int N, int K) {
  constexpr int BN = 256;
  constexpr int MF = BM / 32;                  // m-frags per wave (8 or 4)
  constexpr int MFH = MF / 2;                  // m-frags per phase
  constexpr int A_BYTES = BM * 32 * 2;         // 16384 or 8192
  constexpr int TILE_BYTES = A_BYTES + BN * 32 * 2;  // 32768 or 24576
  constexpr int NLOADS = TILE_BYTES / 8192;    // 4 or 3 (8KB per wave-wide load)
  __shared__ unsigned short lds[4 * (TILE_BYTES / 2)];

  const int tid  = threadIdx.x;
  const int lane = tid & 63;
  const int wid  = tid >> 6;
  const int wm = wid >> 2, wn = wid & 3;
  const int lr = lane & 15, g = lane >> 4;
  const int bm = blockIdx.y * BM;
  const int bn = blockIdx.x * BN;
  const int nt = K >> 5;

  // fragment-read column byte offset with T2 XOR folded in:
  const int cof = (g * 16) ^ ((lr & 6) << 3);

  // stage load j of tile t: linear byte L in [0, TILE_BYTES), A-region then B.
  // Global source column is inverse-swizzled so that swizzled reads see
  // the correct data.
  auto stage_j = [&](int t, int j) {
    const int L = j * 8192 + wid * 1024 + lane * 16;
    const char* src;
    if (L < A_BYTES) {
      const int row = L >> 6;
      const int colb = (L & 63) ^ ((row & 6) << 3);
      src = (const char*)A + ((size_t)(bm + row) * K + t * 32) * 2 + colb;
    } else {
      const int LB = L - A_BYTES;
      const int row = LB >> 6;
      const int colb = (LB & 63) ^ ((row & 6) << 3);
      src = (const char*)B + ((size_t)(bn + row) * K + t * 32) * 2 + colb;
    }
    char* dst = (char*)lds + (t & 3) * TILE_BYTES + L;
    gld_lds16(src, dst);
  };

  // prologue: stage tiles 0,1,2; wait tile 0 landed (tiles 1,2 in flight)
#pragma unroll
  for (int t = 0; t < 3; ++t)
#pragma unroll
    for (int j = 0; j < NLOADS; ++j) stage_j(t, j);
  asm volatile("s_waitcnt vmcnt(%0)" :: "n"(2 * NLOADS) : "memory");
  __builtin_amdgcn_sched_barrier(0);
  __builtin_amdgcn_s_barrier();

  f32x4_t acc[MF][4];
#pragma unroll
  for (int m = 0; m < MF; ++m)
#pragma unroll
    for (int n = 0; n < 4; ++n) acc[m][n] = f32x4_t{0.f, 0.f, 0.f, 0.f};

  bf16x8_t bfr[4];

  for (int t = 0; t < nt; ++t) {
    const char* base = (const char*)lds + (t & 3) * TILE_BYTES;
    const bool st = (t + 3 < nt);

    // ---- phase 0: m-frags [0, MFH), all B-frags ----
    bf16x8_t af[MFH];
#pragma unroll
    for (int m = 0; m < MFH; ++m)
      af[m] = *(const bf16x8_t*)(base + (wm * (BM / 2) + m * 16 + lr) * 64 + cof);
#pragma unroll
    for (int n = 0; n < 4; ++n)
      bfr[n] = *(const bf16x8_t*)(base + A_BYTES + (wn * 64 + n * 16 + lr) * 64 + cof);
    if (st) { stage_j(t + 3, 0); stage_j(t + 3, 1); }
    __builtin_amdgcn_sched_barrier(0);
    __builtin_amdgcn_s_barrier();
    __builtin_amdgcn_s_setprio(1);
#pragma unroll
    for (int m = 0; m < MFH; ++m)
#pragma unroll
      for (int n = 0; n < 4; ++n)
        acc[m][n] = __builtin_amdgcn_mfma_f32_16x16x32_bf16(af[m], bfr[n], acc[m][n], 0, 0, 0);
    __builtin_amdgcn_s_setprio(0);
    __builtin_amdgcn_sched_barrier(0);
    __builtin_amdgcn_s_barrier();

    // ---- phase 1: m-frags [MFH, MF) ----
#pragma unroll
    for (int m = 0; m < MFH; ++m)
      af[m] = *(const bf16x8_t*)(base + (wm * (BM / 2) + (MFH + m) * 16 + lr) * 64 + cof);
    if (st) {
#pragma unroll
      for (int j = 2; j < NLOADS; ++j) stage_j(t + 3, j);
    }
    __builtin_amdgcn_sched_barrier(0);
    __builtin_amdgcn_s_barrier();
    __builtin_amdgcn_s_setprio(1);
#pragma unroll
    for (int m = 0; m < MFH; ++m)
#pragma unroll
      for (int n = 0; n < 4; ++n)
        acc[MFH + m][n] = __builtin_amdgcn_mfma_f32_16x16x32_bf16(af[m], bfr[n], acc[MFH + m][n], 0, 0, 0);
    __builtin_amdgcn_s_setprio(0);

    // ---- tile boundary: counted wait so tile t+1 is resident; never drain ----
    if (t < nt - 3) {
      asm volatile("s_waitcnt vmcnt(%0)" :: "n"(2 * NLOADS) : "memory");
    } else if (t == nt - 3) {
      asm volatile("s_waitcnt vmcnt(%0)" :: "n"(NLOADS) : "memory");
    } else if (t == nt - 2) {
      asm volatile("s_waitcnt vmcnt(0)" ::: "memory");
    }
    __builtin_amdgcn_sched_barrier(0);
    __builtin_amdgcn_s_barrier();
  }

  // ---- epilogue ----
#pragma unroll
  for (int mf = 0; mf < MF; ++mf) {
    const int row0 = bm + wm * (BM / 2) + mf * 16 + g * 4;
#pragma unroll
    for (int nf = 0; nf < 4; ++nf) {
      const int col = bn + wn * 64 + nf * 16 + lr;
      if constexpr (MODE == 1) {
#pragma unroll
        for (int r = 0; r < 4; ++r)
          ((float*)C0)[(size_t)(row0 + r) * N + col] = acc[mf][nf][r];
      } else {
        if (col < HID) {
#pragma unroll
          for (int r = 0; r < 4; ++r)
            ((unsigned short*)C0)[(size_t)(row0 + r) * HID + col] = f2b(acc[mf][nf][r]);
        } else if (col < HID + KVW) {
#pragma unroll
          for (int r = 0; r < 4; ++r)
            ((unsigned short*)C1)[(size_t)(row0 + r) * KVW + (col - HID)] = f2b(acc[mf][nf][r]);
        } else {
          const int c2 = col - HID - KVW;
          ushort4 w;
          w.x = f2b(acc[mf][nf][0]); w.y = f2b(acc[mf][nf][1]);
          w.z = f2b(acc[mf][nf][2]); w.w = f2b(acc[mf][nf][3]);
          *(ushort4*)(void*)&((unsigned short*)C2)[(size_t)c2 * S_LEN + row0] = w;
        }
      }
    }
  }
}

// ---------------- flash attention v2 (causal, GQA 4:1) ----------------
// Swapped QK^T (S^T = mfma(K,Q)): softmax reduce = 2 shfl; wide exp.
// KVBLK=64. V pre-transposed globally (VtG[kv_head*HD + d][s]).
// Block: 64 q rows x 1 head, 4 waves x 16 q rows. Deferred rescale (THR=8).
__global__ __launch_bounds__(256) void attn_kernel(
    const unsigned short* __restrict__ Q, const unsigned short* __restrict__ K,
    const unsigned short* __restrict__ VtG, unsigned short* __restrict__ O) {
  __shared__ unsigned short Kl[64][136];
  __shared__ unsigned short Vt[128][72];
  __shared__ unsigned short Pl[4][16][72];

  const int tid  = threadIdx.x;
  const int lane = tid & 63;
  const int wave = tid >> 6;
  const int h    = blockIdx.y;
  const int kvh  = h >> 2;
  const int q0   = (gridDim.x - 1 - blockIdx.x) * 64;  // heavy blocks first
  const int qrow = q0 + wave * 16;
  const int lr   = lane & 15;
  const int g    = lane >> 4;
  const int lk8  = g * 8;

  bf16x8_t qf[4];
  {
    const unsigned short* qp = Q + (size_t)(qrow + lr) * HID + (size_t)h * HD;
#pragma unroll
    for (int c = 0; c < 4; ++c)
      qf[c] = *(const bf16x8_t*)(const void*)(qp + c * 32 + lk8);
  }

  f32x4_t oacc[8];
#pragma unroll
  for (int c = 0; c < 8; ++c) oacc[c] = f32x4_t{0.f, 0.f, 0.f, 0.f};
  float m_run = -3e38f, l_run = 0.f;

  const float scale = 0.08838834764831845f;  // 1/sqrt(128)
  const int kv_end = q0 + 64;
  const unsigned short* Vbase = VtG + (size_t)kvh * HD * S_LEN;

  const int ksr = tid >> 4, ksc = (tid & 15) * 8;
  const int vsr = tid >> 3, vsc = (tid & 7) * 8;

  for (int kv0 = 0; kv0 < kv_end; kv0 += 64) {
    u16x8_t kr[4], vr[4];
#pragma unroll
    for (int i = 0; i < 4; ++i)
      kr[i] = *(const u16x8_t*)(const void*)(K + (size_t)(kv0 + ksr + i * 16) * KVW +
                                             (size_t)kvh * HD + ksc);
#pragma unroll
    for (int i = 0; i < 4; ++i)
      vr[i] = *(const u16x8_t*)(const void*)(Vbase + (size_t)(vsr + i * 32) * S_LEN +
                                             kv0 + vsc);
    __syncthreads();
#pragma unroll
    for (int i = 0; i < 4; ++i)
      *(u16x8_t*)(void*)&Kl[ksr + i * 16][ksc] = kr[i];
#pragma unroll
    for (int i = 0; i < 4; ++i)
      *(u16x8_t*)(void*)&Vt[vsr + i * 32][vsc] = vr[i];
    __syncthreads();

    f32x4_t sacc[4];
#pragma unroll
    for (int n = 0; n < 4; ++n) sacc[n] = f32x4_t{0.f, 0.f, 0.f, 0.f};
#pragma unroll
    for (int c = 0; c < 4; ++c) {
      bf16x8_t qc = qf[c];
#pragma unroll
      for (int n = 0; n < 4; ++n) {
        bf16x8_t kf = *(const bf16x8_t*)(const void*)&Kl[n * 16 + lr][c * 32 + lk8];
        sacc[n] = __builtin_amdgcn_mfma_f32_16x16x32_bf16(kf, qc, sacc[n], 0, 0, 0);
      }
    }

    const int qg = qrow + lr;
    const bool diag = (kv0 + 63 > qrow);
    float p[16];
    float mloc = -3e38f;
#pragma unroll
    for (int n = 0; n < 4; ++n)
#pragma unroll
      for (int r = 0; r < 4; ++r) {
        float x = sacc[n][r] * scale;
        if (diag) {
          int kg = kv0 + n * 16 + g * 4 + r;
          if (kg > qg) x = -3e38f;
        }
        p[n * 4 + r] = x;
        mloc = fmaxf(mloc, x);
      }
    mloc = fmaxf(mloc, __shfl_xor(mloc, 16));
    mloc = fmaxf(mloc, __shfl_xor(mloc, 32));

    if (__any(mloc > m_run + 8.f)) {
      float m_new = fmaxf(m_run, mloc);
      float alpha = __expf(m_run - m_new);
      float a4[4];
#pragma unroll
      for (int r = 0; r < 4; ++r) a4[r] = __shfl(alpha, g * 4 + r);
#pragma unroll
      for (int c = 0; c < 8; ++c)
#pragma unroll
        for (int r = 0; r < 4; ++r) oacc[c][r] *= a4[r];
      l_run *= alpha;
      m_run = m_new;
    }

    float ssum = 0.f;
#pragma unroll
    for (int i = 0; i < 16; ++i) {
      float e = __expf(p[i] - m_run);
      p[i] = e;
      ssum += e;
    }
    ssum += __shfl_xor(ssum, 16);
    ssum += __shfl_xor(ssum, 32);
    l_run += ssum;

#pragma unroll
    for (int n = 0; n < 4; ++n) {
      ushort4 w;
      w.x = f2b(p[n * 4 + 0]); w.y = f2b(p[n * 4 + 1]);
      w.z = f2b(p[n * 4 + 2]); w.w = f2b(p[n * 4 + 3]);
      *(ushort4*)(void*)&Pl[wave][lr][n * 16 + g * 4] = w;
    }

#pragma unroll
    for (int half = 0; half < 2; ++half) {
      bf16x8_t pf = *(const bf16x8_t*)(const void*)&Pl[wave][lr][half * 32 + lk8];
#pragma unroll
      for (int c = 0; c < 8; ++c) {
        bf16x8_t vf = *(const bf16x8_t*)(const void*)&Vt[c * 16 + lr][half * 32 + lk8];
        oacc[c] = __builtin_amdgcn_mfma_f32_16x16x32_bf16(pf, vf, oacc[c], 0, 0, 0);
      }
    }
  }

  float linv[4];
#pragma unroll
  for (int r = 0; r < 4; ++r) linv[r] = 1.f / __shfl(l_run, g * 4 + r);
#pragma unroll
  for (int r = 0; r < 4; ++r) {
    int row = qrow + g * 4 + r;
#pragma unroll
    for (int c = 0; c < 8; ++c)
      O[(size_t)row * HID + (size_t)h * HD + c * 16 + lr] = f2b(oacc[c][r] * linv[r]);
  }
}

// ---------------- host launch ----------------
extern "C" void kernel_launch(void* const* d_in, const int* in_sizes, int n_in,
                              void* d_out, int out_size, void* d_ws, size_t ws_size,
                              hipStream_t stream) {
  (void)in_sizes; (void)n_in; (void)out_size; (void)ws_size;
  const float* X  = (const float*)d_in[0];
  const float* Wq = (const float*)d_in[1];
  const float* Wk = (const float*)d_in[2];
  const float* Wv = (const float*)d_in[3];
  const float* Wo = (const float*)d_in[4];
  const int*  pos = (const int*)d_in[5];
  float* out = (float*)d_out;

  unsigned short* Xb  = (unsigned short*)d_ws;
  unsigned short* Wqb = Xb  + (size_t)S_LEN * HID;
  unsigned short* Wkb = Wqb + (size_t)HID * HID;    // contiguous with Wqb
  unsigned short* Wvb = Wkb + (size_t)KVW * HID;    // contiguous -> [6144 x 4096] B
  unsigned short* Wob = Wvb + (size_t)KVW * HID;
  unsigned short* Qb  = Wob + (size_t)HID * HID;
  unsigned short* Kb  = Qb  + (size_t)S_LEN * HID;
  unsigned short* VtB = Kb  + (size_t)S_LEN * KVW;  // V^T: [KVW][S_LEN]
  unsigned short* AOb = VtB + (size_t)S_LEN * KVW;

  auto cvt = [&](const float* s, unsigned short* d, size_t n) {
    int n4 = (int)(n / 4);
    int grid = (n4 + 255) / 256;
    if (grid > 4096) grid = 4096;
    cvt_kernel<<<grid, 256, 0, stream>>>(s, d, n4);
  };
  cvt(X,  Xb,  (size_t)S_LEN * HID);
  cvt(Wq, Wqb, (size_t)HID * HID);
  cvt(Wk, Wkb, (size_t)KVW * HID);
  cvt(Wv, Wvb, (size_t)KVW * HID);
  cvt(Wo, Wob, (size_t)HID * HID);

  // QKV projection: 256x256 tiles, grid 24x8 = 192 blocks
  gemm8_kernel<256, 2><<<dim3(QKVN / 256, S_LEN / 256), 512, 0, stream>>>(
      Xb, Wqb, Qb, Kb, VtB, QKVN, HID);

  rope_kernel<<<2048, 256, 0, stream>>>(Qb, Kb, pos);

  attn_kernel<<<dim3(S_LEN / 64, NH), 256, 0, stream>>>(Qb, Kb, VtB, AOb);

  // output projection: 128x256 tiles, grid 16x16 = 256 blocks -> fp32
  gemm8_kernel<128, 1><<<dim3(HID / 256, S_LEN / 128), 512, 0, stream>>>(
      AOb, Wob, out, nullptr, nullptr, HID, HID);
}

// Round 6
// 325.267 us; speedup vs baseline: 2.1854x; 1.2147x over previous
//
#include <hip/hip_runtime.h>
#include <hip/hip_bf16.h>
#include <cstdint>
#include <cstddef>

#define S_LEN 2048
#define HID   4096
#define HD    128
#define NH    32
#define NKV   8
#define KVW   (NKV * HD)        /* 1024 */
#define QKVN  (HID + 2 * KVW)   /* 6144 */

typedef __bf16 bf16x8_t __attribute__((ext_vector_type(8)));
typedef float  f32x4_t  __attribute__((ext_vector_type(4)));
typedef unsigned short u16x8_t __attribute__((ext_vector_type(8)));

__device__ __forceinline__ unsigned short f2b(float f) {
  unsigned u = __float_as_uint(f);
  u += 0x7FFFu + ((u >> 16) & 1u);
  return (unsigned short)(u >> 16);
}
__device__ __forceinline__ float b2f(unsigned short v) {
  return __uint_as_float(((unsigned)v) << 16);
}
__device__ __forceinline__ void gld_lds16(const void* g, void* l) {
  __builtin_amdgcn_global_load_lds(
      (const __attribute__((address_space(1))) void*)g,
      (__attribute__((address_space(3))) void*)l, 16, 0, 0);
}

// ---------------- fp32 -> bf16 conversion ----------------
__global__ void cvt_kernel(const float* __restrict__ src,
                           unsigned short* __restrict__ dst, int n4) {
  int i = blockIdx.x * blockDim.x + threadIdx.x;
  int stride = gridDim.x * blockDim.x;
  for (; i < n4; i += stride) {
    float4 v = reinterpret_cast<const float4*>(src)[i];
    ushort4 o;
    o.x = f2b(v.x); o.y = f2b(v.y); o.z = f2b(v.z); o.w = f2b(v.w);
    reinterpret_cast<ushort4*>(dst)[i] = o;
  }
}

// ---------------- RoPE (in-place on bf16 Q and K) ----------------
__global__ void rope_kernel(unsigned short* __restrict__ Q,
                            unsigned short* __restrict__ Kb,
                            const int* __restrict__ pos_ids) {
  const int total = S_LEN * (NH + NKV) * 64;
  int idx = blockIdx.x * blockDim.x + threadIdx.x;
  int stride = gridDim.x * blockDim.x;
  for (; idx < total; idx += stride) {
    int s   = idx / ((NH + NKV) * 64);
    int rem = idx % ((NH + NKV) * 64);
    int hp  = rem >> 6;
    int i   = rem & 63;
    unsigned short* ptr; int W, h;
    if (hp < NH) { ptr = Q;  W = HID; h = hp; }
    else         { ptr = Kb; W = KVW; h = hp - NH; }
    float pos = (float)pos_ids[s];
    float ang = pos * __expf(-(float)i * 0.14391156516f); // ln(10000)/64
    float sn, cs;
    sincosf(ang, &sn, &cs);
    size_t base = (size_t)s * W + (size_t)h * HD + i;
    float lo = b2f(ptr[base]);
    float hi = b2f(ptr[base + 64]);
    ptr[base]      = f2b(lo * cs - hi * sn);
    ptr[base + 64] = f2b(hi * cs + lo * sn);
  }
}

// ---------------- pipelined GEMM: C = A(MxK) * B(NxK)^T ----------------
// BK=32, 4-deep LDS ring. ONE raw barrier + ONE counted vmcnt per K-tile
// (wait-own-vmcnt BEFORE barrier => all waves' staging proven landed; the
// end-of-tile barrier proves slot (t-1)&3 fully read before overwrite).
// No mid-tile barriers: waves desync inside a tile so ds_read (LDS pipe) of
// one wave overlaps MFMA (matrix pipe) of another.
// T2 swizzle: byte-col ^= (row&6)<<3, applied on BOTH sides (inverse-permuted
// global source in stage + same XOR folded into read offsets).
// 512 threads = 8 waves (2M x 4N). Per-wave output: (BM/2) x 64.
// MODE 1: fp32 out to C0 (ld = N)
// MODE 2: QKV split: cols [0,4096) -> C0 bf16, [4096,5120) -> C1 bf16,
//         [5120,6144) -> C2 = V transposed: C2[(col-5120)*S_LEN+row]
template <int BM, int MODE>
__global__ __launch_bounds__(512, 2) void gemm8_kernel(
    const unsigned short* __restrict__ A, const unsigned short* __restrict__ B,
    void* __restrict__ C0, void* __restrict__ C1, void* __restrict__ C2,
    int N, int K) {
  constexpr int BN = 256;
  constexpr int MF = BM / 32;                  // m-frags per wave (8 or 4)
  constexpr int A_BYTES = BM * 32 * 2;         // 16384 or 8192
  constexpr int TILE_BYTES = A_BYTES + BN * 32 * 2;  // 32768 or 24576
  constexpr int NLOADS = TILE_BYTES / 8192;    // 4 or 3 (8KB per wave-wide load)
  __shared__ unsigned short lds[4 * (TILE_BYTES / 2)];

  const int tid  = threadIdx.x;
  const int lane = tid & 63;
  const int wid  = tid >> 6;
  const int wm = wid >> 2, wn = wid & 3;
  const int lr = lane & 15, g = lane >> 4;
  const int bm = blockIdx.y * BM;
  const int bn = blockIdx.x * BN;
  const int nt = K >> 5;

  // fragment-read column byte offset with T2 XOR folded in:
  const int cof = (g * 16) ^ ((lr & 6) << 3);

  auto stage_j = [&](int t, int j) {
    const int L = j * 8192 + wid * 1024 + lane * 16;
    const char* src;
    if (L < A_BYTES) {
      const int row = L >> 6;
      const int colb = (L & 63) ^ ((row & 6) << 3);
      src = (const char*)A + ((size_t)(bm + row) * K + t * 32) * 2 + colb;
    } else {
      const int LB = L - A_BYTES;
      const int row = LB >> 6;
      const int colb = (LB & 63) ^ ((row & 6) << 3);
      src = (const char*)B + ((size_t)(bn + row) * K + t * 32) * 2 + colb;
    }
    char* dst = (char*)lds + (t & 3) * TILE_BYTES + L;
    gld_lds16(src, dst);
  };

  // prologue: stage tiles 0,1,2; wait own tile-0 loads; barrier => tile 0 ready
#pragma unroll
  for (int t = 0; t < 3; ++t)
#pragma unroll
    for (int j = 0; j < NLOADS; ++j) stage_j(t, j);
  asm volatile("s_waitcnt vmcnt(%0)" :: "n"(2 * NLOADS) : "memory");
  __builtin_amdgcn_sched_barrier(0);
  __builtin_amdgcn_s_barrier();

  f32x4_t acc[MF][4];
#pragma unroll
  for (int m = 0; m < MF; ++m)
#pragma unroll
    for (int n = 0; n < 4; ++n) acc[m][n] = f32x4_t{0.f, 0.f, 0.f, 0.f};

  for (int t = 0; t < nt; ++t) {
    const char* base = (const char*)lds + (t & 3) * TILE_BYTES;

    // issue next staging early (writes slot (t-1)&3: proven read-complete)
    if (t + 3 < nt) {
#pragma unroll
      for (int j = 0; j < NLOADS; ++j) stage_j(t + 3, j);
    }

    // all fragments for this tile
    bf16x8_t af[MF], bfr[4];
#pragma unroll
    for (int m = 0; m < MF; ++m)
      af[m] = *(const bf16x8_t*)(base + (wm * (BM / 2) + m * 16 + lr) * 64 + cof);
#pragma unroll
    for (int n = 0; n < 4; ++n)
      bfr[n] = *(const bf16x8_t*)(base + A_BYTES + (wn * 64 + n * 16 + lr) * 64 + cof);
    asm volatile("s_waitcnt lgkmcnt(0)" ::: "memory");
    __builtin_amdgcn_sched_barrier(0);

    __builtin_amdgcn_s_setprio(1);
#pragma unroll
    for (int m = 0; m < MF; ++m)
#pragma unroll
      for (int n = 0; n < 4; ++n)
        acc[m][n] = __builtin_amdgcn_mfma_f32_16x16x32_bf16(af[m], bfr[n], acc[m][n], 0, 0, 0);
    __builtin_amdgcn_s_setprio(0);
    __builtin_amdgcn_sched_barrier(0);

    // tile boundary: own-vmcnt wait (next tile landed) BEFORE barrier
    if (t < nt - 3) {
      asm volatile("s_waitcnt vmcnt(%0)" :: "n"(2 * NLOADS) : "memory");
    } else if (t == nt - 3) {
      asm volatile("s_waitcnt vmcnt(%0)" :: "n"(NLOADS) : "memory");
    } else if (t == nt - 2) {
      asm volatile("s_waitcnt vmcnt(0)" ::: "memory");
    }
    __builtin_amdgcn_sched_barrier(0);
    __builtin_amdgcn_s_barrier();
  }

  // ---- epilogue ----
#pragma unroll
  for (int mf = 0; mf < MF; ++mf) {
    const int row0 = bm + wm * (BM / 2) + mf * 16 + g * 4;
#pragma unroll
    for (int nf = 0; nf < 4; ++nf) {
      const int col = bn + wn * 64 + nf * 16 + lr;
      if constexpr (MODE == 1) {
#pragma unroll
        for (int r = 0; r < 4; ++r)
          ((float*)C0)[(size_t)(row0 + r) * N + col] = acc[mf][nf][r];
      } else {
        if (col < HID) {
#pragma unroll
          for (int r = 0; r < 4; ++r)
            ((unsigned short*)C0)[(size_t)(row0 + r) * HID + col] = f2b(acc[mf][nf][r]);
        } else if (col < HID + KVW) {
#pragma unroll
          for (int r = 0; r < 4; ++r)
            ((unsigned short*)C1)[(size_t)(row0 + r) * KVW + (col - HID)] = f2b(acc[mf][nf][r]);
        } else {
          const int c2 = col - HID - KVW;
          ushort4 w;
          w.x = f2b(acc[mf][nf][0]); w.y = f2b(acc[mf][nf][1]);
          w.z = f2b(acc[mf][nf][2]); w.w = f2b(acc[mf][nf][3]);
          *(ushort4*)(void*)&((unsigned short*)C2)[(size_t)c2 * S_LEN + row0] = w;
        }
      }
    }
  }
}

// ---------------- flash attention v3 (causal, GQA 4:1) ----------------
// Folded load balance: block pair p handles q-blocks {31-p, p} sequentially
// => constant 33 tiles/block, grid 16 x 32 heads = 512 uniform blocks.
// T14 prefetch: K/V tile t+1 global->reg issued right after tile t ds_writes;
// latency hides under QK+softmax+PV. Raw barriers + manual lgkmcnt only
// (no __syncthreads => prefetch vmcnt never drained).
__global__ __launch_bounds__(256) void attn_kernel(
    const unsigned short* __restrict__ Q, const unsigned short* __restrict__ K,
    const unsigned short* __restrict__ VtG, unsigned short* __restrict__ O) {
  __shared__ unsigned short Kl[64][136];
  __shared__ unsigned short Vt[128][72];
  __shared__ unsigned short Pl[4][16][72];

  const int tid  = threadIdx.x;
  const int lane = tid & 63;
  const int wave = tid >> 6;
  const int h    = blockIdx.y;
  const int kvh  = h >> 2;
  const int pair = blockIdx.x;             // [0,16)
  const int lr   = lane & 15;
  const int g    = lane >> 4;
  const int lk8  = g * 8;
  const float scale = 0.08838834764831845f;  // 1/sqrt(128)
  const unsigned short* Vbase = VtG + (size_t)kvh * HD * S_LEN;

  const int ksr = tid >> 4, ksc = (tid & 15) * 8;   // K stage: 16 rows x 128 cols
  const int vsr = tid >> 3, vsc = (tid & 7) * 8;    // Vt stage: 32 rows x 64 cols

  for (int pass = 0; pass < 2; ++pass) {
    const int qb = pass == 0 ? (31 - pair) : pair;
    const int q0 = qb * 64;
    const int qrow = q0 + wave * 16;
    const int nkv = qb + 1;

    bf16x8_t qf[4];
    {
      const unsigned short* qp = Q + (size_t)(qrow + lr) * HID + (size_t)h * HD;
#pragma unroll
      for (int c = 0; c < 4; ++c)
        qf[c] = *(const bf16x8_t*)(const void*)(qp + c * 32 + lk8);
    }
    f32x4_t oacc[8];
#pragma unroll
    for (int c = 0; c < 8; ++c) oacc[c] = f32x4_t{0.f, 0.f, 0.f, 0.f};
    float m_run = -3e38f, l_run = 0.f;

    // prologue: load tile 0 into regs
    u16x8_t kr[4], vr[4];
#pragma unroll
    for (int i = 0; i < 4; ++i)
      kr[i] = *(const u16x8_t*)(const void*)(K + (size_t)(ksr + i * 16) * KVW +
                                             (size_t)kvh * HD + ksc);
#pragma unroll
    for (int i = 0; i < 4; ++i)
      vr[i] = *(const u16x8_t*)(const void*)(Vbase + (size_t)(vsr + i * 32) * S_LEN + vsc);

    for (int it = 0; it < nkv; ++it) {
      const int kv0 = it * 64;
      // all waves done reading previous tile's LDS
      __builtin_amdgcn_s_barrier();
      // write tile it (compiler inserts vmcnt waits for kr/vr here)
#pragma unroll
      for (int i = 0; i < 4; ++i)
        *(u16x8_t*)(void*)&Kl[ksr + i * 16][ksc] = kr[i];
#pragma unroll
      for (int i = 0; i < 4; ++i)
        *(u16x8_t*)(void*)&Vt[vsr + i * 32][vsc] = vr[i];
      // prefetch tile it+1 into regs (hidden under compute below)
      if (it + 1 < nkv) {
        const int kn = kv0 + 64;
#pragma unroll
        for (int i = 0; i < 4; ++i)
          kr[i] = *(const u16x8_t*)(const void*)(K + (size_t)(kn + ksr + i * 16) * KVW +
                                                 (size_t)kvh * HD + ksc);
#pragma unroll
        for (int i = 0; i < 4; ++i)
          vr[i] = *(const u16x8_t*)(const void*)(Vbase + (size_t)(vsr + i * 32) * S_LEN +
                                                 kn + vsc);
      }
      asm volatile("s_waitcnt lgkmcnt(0)" ::: "memory");
      __builtin_amdgcn_sched_barrier(0);
      __builtin_amdgcn_s_barrier();   // tile it visible to all

      // ---- S^T = K * Q^T : acc col = q (lane&15), row = k (g*4+r + 16n) ----
      f32x4_t sacc[4];
#pragma unroll
      for (int n = 0; n < 4; ++n) sacc[n] = f32x4_t{0.f, 0.f, 0.f, 0.f};
#pragma unroll
      for (int c = 0; c < 4; ++c) {
        bf16x8_t qc = qf[c];
#pragma unroll
        for (int n = 0; n < 4; ++n) {
          bf16x8_t kf = *(const bf16x8_t*)(const void*)&Kl[n * 16 + lr][c * 32 + lk8];
          sacc[n] = __builtin_amdgcn_mfma_f32_16x16x32_bf16(kf, qc, sacc[n], 0, 0, 0);
        }
      }

      // ---- softmax over k (register-local 16 + 2 shfl) ----
      const int qg = qrow + lr;
      const bool diag = (it == nkv - 1);
      float p[16];
      float mloc = -3e38f;
#pragma unroll
      for (int n = 0; n < 4; ++n)
#pragma unroll
        for (int r = 0; r < 4; ++r) {
          float x = sacc[n][r] * scale;
          if (diag) {
            int kg = kv0 + n * 16 + g * 4 + r;
            if (kg > qg) x = -3e38f;
          }
          p[n * 4 + r] = x;
          mloc = fmaxf(mloc, x);
        }
      mloc = fmaxf(mloc, __shfl_xor(mloc, 16));
      mloc = fmaxf(mloc, __shfl_xor(mloc, 32));

      if (__any(mloc > m_run + 8.f)) {          // T13 deferred rescale
        float m_new = fmaxf(m_run, mloc);
        float alpha = __expf(m_run - m_new);
        float a4[4];
#pragma unroll
        for (int r = 0; r < 4; ++r) a4[r] = __shfl(alpha, g * 4 + r);
#pragma unroll
        for (int c = 0; c < 8; ++c)
#pragma unroll
          for (int r = 0; r < 4; ++r) oacc[c][r] *= a4[r];
        l_run *= alpha;
        m_run = m_new;
      }

      float ssum = 0.f;
#pragma unroll
      for (int i = 0; i < 16; ++i) {
        float e = __expf(p[i] - m_run);
        p[i] = e;
        ssum += e;
      }
      ssum += __shfl_xor(ssum, 16);
      ssum += __shfl_xor(ssum, 32);
      l_run += ssum;

      // ---- store P (transpose S^T -> row-major P[q][k]), wave-local ----
#pragma unroll
      for (int n = 0; n < 4; ++n) {
        ushort4 w;
        w.x = f2b(p[n * 4 + 0]); w.y = f2b(p[n * 4 + 1]);
        w.z = f2b(p[n * 4 + 2]); w.w = f2b(p[n * 4 + 3]);
        *(ushort4*)(void*)&Pl[wave][lr][n * 16 + g * 4] = w;
      }

      // ---- PV: out += P * V ----
#pragma unroll
      for (int half = 0; half < 2; ++half) {
        bf16x8_t pf = *(const bf16x8_t*)(const void*)&Pl[wave][lr][half * 32 + lk8];
#pragma unroll
        for (int c = 0; c < 8; ++c) {
          bf16x8_t vf = *(const bf16x8_t*)(const void*)&Vt[c * 16 + lr][half * 32 + lk8];
          oacc[c] = __builtin_amdgcn_mfma_f32_16x16x32_bf16(pf, vf, oacc[c], 0, 0, 0);
        }
      }
    }

    // ---- epilogue for this pass ----
    float linv[4];
#pragma unroll
    for (int r = 0; r < 4; ++r) linv[r] = 1.f / __shfl(l_run, g * 4 + r);
#pragma unroll
    for (int r = 0; r < 4; ++r) {
      int row = qrow + g * 4 + r;
#pragma unroll
      for (int c = 0; c < 8; ++c)
        O[(size_t)row * HID + (size_t)h * HD + c * 16 + lr] = f2b(oacc[c][r] * linv[r]);
    }
  }
}

// ---------------- host launch ----------------
extern "C" void kernel_launch(void* const* d_in, const int* in_sizes, int n_in,
                              void* d_out, int out_size, void* d_ws, size_t ws_size,
                              hipStream_t stream) {
  (void)in_sizes; (void)n_in; (void)out_size; (void)ws_size;
  const float* X  = (const float*)d_in[0];
  const float* Wq = (const float*)d_in[1];
  const float* Wk = (const float*)d_in[2];
  const float* Wv = (const float*)d_in[3];
  const float* Wo = (const float*)d_in[4];
  const int*  pos = (const int*)d_in[5];
  float* out = (float*)d_out;

  unsigned short* Xb  = (unsigned short*)d_ws;
  unsigned short* Wqb = Xb  + (size_t)S_LEN * HID;
  unsigned short* Wkb = Wqb + (size_t)HID * HID;    // contiguous with Wqb
  unsigned short* Wvb = Wkb + (size_t)KVW * HID;    // contiguous -> [6144 x 4096] B
  unsigned short* Wob = Wvb + (size_t)KVW * HID;
  unsigned short* Qb  = Wob + (size_t)HID * HID;
  unsigned short* Kb  = Qb  + (size_t)S_LEN * HID;
  unsigned short* VtB = Kb  + (size_t)S_LEN * KVW;  // V^T: [KVW][S_LEN]
  unsigned short* AOb = VtB + (size_t)S_LEN * KVW;

  auto cvt = [&](const float* s, unsigned short* d, size_t n) {
    int n4 = (int)(n / 4);
    int grid = (n4 + 255) / 256;
    if (grid > 4096) grid = 4096;
    cvt_kernel<<<grid, 256, 0, stream>>>(s, d, n4);
  };
  cvt(X,  Xb,  (size_t)S_LEN * HID);
  cvt(Wq, Wqb, (size_t)HID * HID);
  cvt(Wk, Wkb, (size_t)KVW * HID);
  cvt(Wv, Wvb, (size_t)KVW * HID);
  cvt(Wo, Wob, (size_t)HID * HID);

  // QKV projection: 256x256 tiles, grid 24x8 = 192 blocks
  gemm8_kernel<256, 2><<<dim3(QKVN / 256, S_LEN / 256), 512, 0, stream>>>(
      Xb, Wqb, Qb, Kb, VtB, QKVN, HID);

  rope_kernel<<<2048, 256, 0, stream>>>(Qb, Kb, pos);

  // folded-balance attention: 16 pair-blocks x 32 heads
  attn_kernel<<<dim3(16, NH), 256, 0, stream>>>(Qb, Kb, VtB, AOb);

  // output projection: 128x256 tiles, grid 16x16 = 256 blocks -> fp32
  gemm8_kernel<128, 1><<<dim3(HID / 256, S_LEN / 128), 512, 0, stream>>>(
      AOb, Wob, out, nullptr, nullptr, HID, HID);
}